// Round 1
// baseline (1462.554 us; speedup 1.0000x reference)
//
#include <hip/hip_runtime.h>

// Problem constants
// x: (1024, 28, 64, 28) f32   [l, k, i, j]
// W: (128, 3, 32, 3)    f32   [co, kh, u, kw]
// out: (1024, 128, 28, 28) f32
//
// out[l,co,n,o] = sum_{kh,u,kw} W[co,kh,u,kw] * T6[l,kh,n,u,o+kw-1]
// T6[l,kh,p,u,v] = V(h=(p+27)%28,c=1) + V(h=p,c=0)
//   V(h,c): hh=h+kh-1; if hh in [0,28): q=8*hh+4c+u; X[l, q%28, 2*hh+c+q/28, v]

#define X_L 1024
#define OUT_CO 128
#define P_N 28

// Transpose W[co][kh][u][kw] -> Wt[kh][u][kw][co] (36864 floats)
__global__ void wt_transpose_kernel(const float* __restrict__ W, float* __restrict__ Wt) {
    int id = blockIdx.x * 256 + threadIdx.x;   // 0..36863
    if (id >= 36864) return;
    int co = id & 127;
    int r  = id >> 7;          // 0..287 = (kh*32+u)*3+kw
    int kw = r % 3;
    int r2 = r / 3;            // 0..95 = kh*32+u
    int u  = r2 & 31;
    int kh = r2 >> 5;
    Wt[id] = W[(co * 288) + kh * 96 + u * 3 + kw];
}

// v2: 2 l-values per block (two T6 tiles in LDS), each thread computes 8co x 7o.
// Per (kh,u): 168 FMA vs 9 LDS reads + 6 float4 W loads -> ~2x FMA issue density vs v1.
template <bool USE_WT>
__global__ __launch_bounds__(128, 3) void fused_shiftconv_kernel(
        const float* __restrict__ x,
        const float* __restrict__ Wsrc,   // Wt if USE_WT else original W
        float* __restrict__ out) {
    // Two T6 tiles (one per l), padded: [kh][u][pv], pv = v+1, row stride 32
    __shared__ float T6L[2][3 * 32 * 32];   // 24 KB

    const int p   = blockIdx.x;       // 0..27
    const int l0  = blockIdx.y * 2;   // 0,2,..,1022
    const int tid = threadIdx.x;      // 0..127
    const int h1  = (p + 27) % 28;

    // ---- build both T6 tiles ----
    for (int lsb = 0; lsb < 2; ++lsb) {
        const float* __restrict__ xl = x + (size_t)(l0 + lsb) * (28 * 64 * 28);
        for (int e = tid; e < 3072; e += 128) {
            int kh = e >> 10;
            int u  = (e >> 5) & 31;
            int pv = e & 31;
            int v  = pv - 1;
            float val = 0.f;
            if (v >= 0 && v < 28) {
                int hh0 = p + kh - 1;
                if (hh0 >= 0 && hh0 < 28) {
                    int q  = 8 * hh0 + u;               // < 248
                    int k0 = q % 28;
                    int i0 = 2 * hh0 + (q / 28);
                    val += xl[(k0 * 64 + i0) * 28 + v];
                }
                int hh1 = h1 + kh - 1;
                if (hh1 >= 0 && hh1 < 28) {
                    int q  = 8 * hh1 + 4 + u;           // < 252
                    int k1 = q % 28;
                    int i1 = 2 * hh1 + 1 + (q / 28);
                    val += xl[(k1 * 64 + i1) * 28 + v];
                }
            }
            T6L[lsb][e] = val;
        }
    }
    __syncthreads();

    // ---- compute: thread = (g: 8 co) x (hq: 7 o) x (ls: which l) ----
    const int g   = tid & 15;         // co = 8g + m
    const int hq  = (tid >> 4) & 3;   // o  = 7*hq + d
    const int ls  = tid >> 6;         // wave 0 -> l0, wave 1 -> l0+1
    const int ob  = 7 * hq;
    const int co0 = 8 * g;

    float acc[8][7];
    #pragma unroll
    for (int m = 0; m < 8; ++m)
        #pragma unroll
        for (int d = 0; d < 7; ++d) acc[m][d] = 0.f;

    const float* tl = &T6L[ls][ob];

    if (USE_WT) {
        const float* wp = Wsrc + co0;           // Wt[kh][u][kw][co]
        #pragma unroll 4
        for (int r = 0; r < 96; ++r) {          // r = kh*32 + u
            float tv[9];
            #pragma unroll
            for (int t2 = 0; t2 < 9; ++t2) tv[t2] = tl[t2];

            float4 wa[3], wb[3];
            #pragma unroll
            for (int kw = 0; kw < 3; ++kw) {
                wa[kw] = *(const float4*)(wp + (kw << 7));
                wb[kw] = *(const float4*)(wp + (kw << 7) + 4);
            }

            #pragma unroll
            for (int kw = 0; kw < 3; ++kw) {
                #pragma unroll
                for (int d = 0; d < 7; ++d) {
                    const float t = tv[d + kw];
                    acc[0][d] += wa[kw].x * t;
                    acc[1][d] += wa[kw].y * t;
                    acc[2][d] += wa[kw].z * t;
                    acc[3][d] += wa[kw].w * t;
                    acc[4][d] += wb[kw].x * t;
                    acc[5][d] += wb[kw].y * t;
                    acc[6][d] += wb[kw].z * t;
                    acc[7][d] += wb[kw].w * t;
                }
            }
            tl += 32;
            wp += 384;
        }
    } else {
        // correctness fallback: original W layout [co][kh*96 + u*3 + kw]
        for (int r = 0; r < 96; ++r) {
            float tv[9];
            #pragma unroll
            for (int t2 = 0; t2 < 9; ++t2) tv[t2] = tl[t2];

            #pragma unroll
            for (int kw = 0; kw < 3; ++kw) {
                #pragma unroll
                for (int m = 0; m < 8; ++m) {
                    const float w = Wsrc[(co0 + m) * 288 + 3 * r + kw];
                    #pragma unroll
                    for (int d = 0; d < 7; ++d)
                        acc[m][d] += w * tv[d + kw];
                }
            }
            tl += 32;
        }
    }

    // ---- store ----
    const size_t base = (((size_t)(l0 + ls) * 128 + co0) * 28 + p) * 28 + ob;
    #pragma unroll
    for (int m = 0; m < 8; ++m) {
        #pragma unroll
        for (int d = 0; d < 7; ++d)
            out[base + (size_t)m * 784 + d] = acc[m][d];
    }
}

extern "C" void kernel_launch(void* const* d_in, const int* in_sizes, int n_in,
                              void* d_out, int out_size, void* d_ws, size_t ws_size,
                              hipStream_t stream) {
    (void)in_sizes; (void)n_in; (void)out_size;
    const float* x = (const float*)d_in[0];
    const float* W = (const float*)d_in[1];
    float* out = (float*)d_out;

    const dim3 grid(28, 512);
    const dim3 block(128);

    if (ws_size >= 36864 * sizeof(float)) {
        float* Wt = (float*)d_ws;
        wt_transpose_kernel<<<144, 256, 0, stream>>>(W, Wt);
        fused_shiftconv_kernel<true><<<grid, block, 0, stream>>>(x, Wt, out);
    } else {
        fused_shiftconv_kernel<false><<<grid, block, 0, stream>>>(x, W, out);
    }
}

// Round 2
// 666.817 us; speedup vs baseline: 2.1933x; 2.1933x over previous
//
#include <hip/hip_runtime.h>

// x: (1024, 28, 64, 28) f32   [l, k, i, j]
// W: (128, 3, 32, 3)    f32   [co, kh, u, kw]
// out: (1024, 128, 28, 28) f32
//
// out[l,co,p,o] = sum_{kw} sum_{r=(kh,u)} W[co,kh,u,kw] * T6[l,r,p,o+kw-1]
// T6[l,(kh,u),p,v] = V(h=(p+27)%28,c=1) + V(h=p,c=0)
//   V(h,c): hh=h+kh-1; if hh in [0,28): q=8*hh+4c+u; X[l, q%28, 2*hh+c+q/28, v]
//
// MFMA formulation (f16 inputs, f32 accumulate):
//   per (l, 4-p tile): out(128 x 128cols) = sum_kw A_kw(128x96) * B_kw(96x128)
//   B_kw columns: col(p_loc, o) reads LDS T6[p_loc][pv = o + kw][r], pv = v+1.

typedef _Float16 f16x8 __attribute__((ext_vector_type(8)));
typedef float    f32x4 __attribute__((ext_vector_type(4)));

#define PG  4     // p's per block
#define PVN 36    // padded pv extent (pv = o + kw reaches 33)
#define RP  104   // r-stride in halves (96 padded -> 2-way banks on b128 reads)

// ---- W prep: W[co][kh][u][kw] f32 -> Ah[(kw*128+co)*96 + r] f16, r = kh*32+u
__global__ void w_prep_kernel(const float* __restrict__ W, _Float16* __restrict__ Ah) {
    int id = blockIdx.x * 256 + threadIdx.x;   // 0..36863
    if (id >= 3 * 128 * 96) return;
    int r  = id % 96;
    int t  = id / 96;          // kw*128 + co
    int co = t & 127;
    int kw = t >> 7;
    Ah[id] = (_Float16)W[co * 288 + (r >> 5) * 96 + (r & 31) * 3 + kw];
}

__global__ __launch_bounds__(256, 3) void mfma_shiftconv_kernel(
        const float* __restrict__ x,
        const _Float16* __restrict__ Ah,
        float* __restrict__ out) {
    __shared__ _Float16 T6L[PG * PVN * RP];    // 29952 B

    const int p0  = blockIdx.x * PG;           // 0,4,..,24
    const int l   = blockIdx.y;                // 0..1023
    const int tid = threadIdx.x;               // 0..255
    const float* __restrict__ xl = x + (size_t)l * (28 * 64 * 28);

    // ---- zero LDS (covers conv padding pv=0 and pv>=29, plus r-pad) ----
    {
        f32x4 z = {0.f, 0.f, 0.f, 0.f};
        f32x4* T4 = (f32x4*)T6L;
        for (int i = tid; i < (PG * PVN * RP) / 8; i += 256) T4[i] = z;
    }
    __syncthreads();

    // ---- fill T6 tile: one (p_loc, r) row of 28 v-values per iteration ----
    for (int pr = tid; pr < PG * 96; pr += 256) {
        int p_loc = pr / 96;
        int r     = pr % 96;
        int kh    = r >> 5;
        int u     = r & 31;
        int p_abs = p0 + p_loc;
        int h1    = (p_abs + 27) % 28;

        const float* s0 = nullptr;
        const float* s1 = nullptr;
        int hh0 = p_abs + kh - 1;
        if (hh0 >= 0 && hh0 < 28) {
            int q = 8 * hh0 + u;                       // < 248
            s0 = xl + ((q % 28) * 64 + 2 * hh0 + (q / 28)) * 28;
        }
        int hh1 = h1 + kh - 1;
        if (hh1 >= 0 && hh1 < 28) {
            int q = 8 * hh1 + 4 + u;                   // < 252
            s1 = xl + ((q % 28) * 64 + 2 * hh1 + 1 + (q / 28)) * 28;
        }

        _Float16* dst = &T6L[(p_loc * PVN + 1) * RP + r];   // pv = 1 + v
        #pragma unroll
        for (int v = 0; v < 28; v += 4) {
            f32x4 a = {0.f, 0.f, 0.f, 0.f};
            f32x4 b = {0.f, 0.f, 0.f, 0.f};
            if (s0) a = *(const f32x4*)(s0 + v);
            if (s1) b = *(const f32x4*)(s1 + v);
            dst[(v + 0) * RP] = (_Float16)(a.x + b.x);
            dst[(v + 1) * RP] = (_Float16)(a.y + b.y);
            dst[(v + 2) * RP] = (_Float16)(a.z + b.z);
            dst[(v + 3) * RP] = (_Float16)(a.w + b.w);
        }
    }
    __syncthreads();

    // ---- GEMM: 2x2 wave grid. wave = (wm: co half) x (wn: col half) ----
    const int lane = tid & 63;
    const int wid  = tid >> 6;
    const int wm   = wid >> 1;       // co block of 64
    const int wn   = wid & 1;        // column block of 64 (2 p's)
    const int ln   = lane & 15;
    const int kb   = lane >> 4;      // 0..3 -> k sub-block of 8

    f32x4 acc[4][4];
    {
        f32x4 zz = {0.f, 0.f, 0.f, 0.f};
        #pragma unroll
        for (int a2 = 0; a2 < 4; ++a2)
            #pragma unroll
            for (int b2 = 0; b2 < 4; ++b2) acc[a2][b2] = zz;
    }

    #pragma unroll
    for (int kw = 0; kw < 3; ++kw) {
        #pragma unroll
        for (int kf = 0; kf < 3; ++kf) {
            const int rr = 32 * kf + 8 * kb;
            f16x8 afr[4];
            #pragma unroll
            for (int mf = 0; mf < 4; ++mf) {
                int co = 64 * wm + 16 * mf + ln;        // A: lane&15 = co row
                afr[mf] = *(const f16x8*)(Ah + ((kw * 128 + co) * 96 + rr));
            }
            #pragma unroll
            for (int nfl = 0; nfl < 4; ++nfl) {
                int nf = 4 * wn + nfl;                  // 0..7
                int pv = (nf & 1) * 16 + ln + kw;       // B: lane&15 = col
                f16x8 bfr = *(const f16x8*)&T6L[((nf >> 1) * PVN + pv) * RP + rr];
                #pragma unroll
                for (int mf = 0; mf < 4; ++mf)
                    acc[mf][nfl] = __builtin_amdgcn_mfma_f32_16x16x32_f16(
                        afr[mf], bfr, acc[mf][nfl], 0, 0, 0);
            }
        }
    }

    // ---- store: C/D mapping col=lane&15, row=(lane>>4)*4+q ----
    #pragma unroll
    for (int nfl = 0; nfl < 4; ++nfl) {
        int nf = 4 * wn + nfl;
        int o  = (nf & 1) * 16 + ln;
        if (o < 28) {
            int p_abs = p0 + (nf >> 1);
            #pragma unroll
            for (int mf = 0; mf < 4; ++mf) {
                int co = 64 * wm + 16 * mf + 4 * kb;
                float* op = out + (((size_t)l * 128 + co) * 28 + p_abs) * 28 + o;
                #pragma unroll
                for (int q = 0; q < 4; ++q) op[(size_t)q * 784] = acc[mf][nfl][q];
            }
        }
    }
}

// ---- fallback (ws too small): known-good v1 f32 kernel, direct W reads ----
__global__ void fallback_shiftconv_kernel(
        const float* __restrict__ x,
        const float* __restrict__ W,
        float* __restrict__ out) {
    __shared__ float T6F[3 * 32 * 32];

    const int p = blockIdx.x;
    const int l = blockIdx.y;
    const int tid = threadIdx.x;   // 0..127

    const float* __restrict__ xl = x + (size_t)l * (28 * 64 * 28);
    const int h1 = (p + 27) % 28;

    for (int e = tid; e < 3072; e += 128) {
        int kh = e >> 10;
        int u  = (e >> 5) & 31;
        int pv = e & 31;
        int v  = pv - 1;
        float val = 0.f;
        if (v >= 0 && v < 28) {
            int hh0 = p + kh - 1;
            if (hh0 >= 0 && hh0 < 28) {
                int q  = 8 * hh0 + u;
                val += xl[((q % 28) * 64 + 2 * hh0 + (q / 28)) * 28 + v];
            }
            int hh1 = h1 + kh - 1;
            if (hh1 >= 0 && hh1 < 28) {
                int q  = 8 * hh1 + 4 + u;
                val += xl[((q % 28) * 64 + 2 * hh1 + 1 + (q / 28)) * 28 + v];
            }
        }
        T6F[e] = val;
    }
    __syncthreads();

    const int g  = tid & 31;
    const int hq = tid >> 5;
    const int ob = 7 * hq;

    float acc[4][7];
    #pragma unroll
    for (int m = 0; m < 4; ++m)
        #pragma unroll
        for (int d = 0; d < 7; ++d) acc[m][d] = 0.f;

    for (int kh = 0; kh < 3; ++kh) {
        for (int u = 0; u < 32; ++u) {
            const float* tl = &T6F[(kh * 32 + u) * 32 + ob];
            float tv[9];
            #pragma unroll
            for (int t2 = 0; t2 < 9; ++t2) tv[t2] = tl[t2];

            #pragma unroll
            for (int kw = 0; kw < 3; ++kw) {
                const int off = kh * 96 + u * 3 + kw;
                float w0 = W[(4 * g + 0) * 288 + off];
                float w1 = W[(4 * g + 1) * 288 + off];
                float w2 = W[(4 * g + 2) * 288 + off];
                float w3 = W[(4 * g + 3) * 288 + off];
                #pragma unroll
                for (int d = 0; d < 7; ++d) {
                    const float t = tv[d + kw];
                    acc[0][d] += w0 * t;
                    acc[1][d] += w1 * t;
                    acc[2][d] += w2 * t;
                    acc[3][d] += w3 * t;
                }
            }
        }
    }

    const size_t base = (((size_t)l * 128 + 4 * g) * 28 + p) * 28 + ob;
    #pragma unroll
    for (int m = 0; m < 4; ++m)
        #pragma unroll
        for (int d = 0; d < 7; ++d)
            out[base + (size_t)m * 784 + d] = acc[m][d];
}

extern "C" void kernel_launch(void* const* d_in, const int* in_sizes, int n_in,
                              void* d_out, int out_size, void* d_ws, size_t ws_size,
                              hipStream_t stream) {
    (void)in_sizes; (void)n_in; (void)out_size;
    const float* x = (const float*)d_in[0];
    const float* W = (const float*)d_in[1];
    float* out = (float*)d_out;

    if (ws_size >= 36864 * sizeof(_Float16)) {
        _Float16* Ah = (_Float16*)d_ws;
        w_prep_kernel<<<144, 256, 0, stream>>>(W, Ah);
        mfma_shiftconv_kernel<<<dim3(7, 1024), 256, 0, stream>>>(x, Ah, out);
    } else {
        fallback_shiftconv_kernel<<<dim3(28, 1024), 128, 0, stream>>>(x, W, out);
    }
}